// Round 1
// baseline (567.576 us; speedup 1.0000x reference)
//
#include <hip/hip_runtime.h>

// Problem: y[b,s,n] = sum_k x[b,s,k] * (wq[n,k]*scale[blk(n,k)]) + bias[n]
// M = 2*4096 = 8192, N = 4096, K = 4096.  fp32 in/out.
// Strategy: pre-convert x -> bf16 and dequant w -> bf16 into d_ws (100.7 MB),
// then m97-structure bf16 MFMA GEMM (128x128 tile, BK=32, global_load_lds).

#define M_DIM 8192
#define N_DIM 4096
#define K_DIM 4096

typedef short s16x8 __attribute__((ext_vector_type(8)));   // 8 bf16 in 4 VGPRs
typedef float f32x4 __attribute__((ext_vector_type(4)));

__device__ __forceinline__ unsigned short f32_to_bf16(float f) {
    // round-to-nearest-even
    unsigned int u = __float_as_uint(f);
    unsigned int r = (u + 0x7fffu + ((u >> 16) & 1u)) >> 16;
    return (unsigned short)r;
}

// ---- pre-pass 1: x fp32 -> bf16 (8 elems/thread, 32B in / 16B out) ----
__global__ __launch_bounds__(256) void cvt_x_kernel(
    const float4* __restrict__ in, s16x8* __restrict__ out) {
    int i = blockIdx.x * 256 + threadIdx.x;
    float4 a = in[2 * i];
    float4 b = in[2 * i + 1];
    s16x8 r;
    r[0] = (short)f32_to_bf16(a.x); r[1] = (short)f32_to_bf16(a.y);
    r[2] = (short)f32_to_bf16(a.z); r[3] = (short)f32_to_bf16(a.w);
    r[4] = (short)f32_to_bf16(b.x); r[5] = (short)f32_to_bf16(b.y);
    r[6] = (short)f32_to_bf16(b.z); r[7] = (short)f32_to_bf16(b.w);
    out[i] = r;
}

// ---- pre-pass 2: w dequant fp32*scale -> bf16 (8 elems/thread, one block scale) ----
__global__ __launch_bounds__(256) void cvt_w_kernel(
    const float4* __restrict__ wq, const float* __restrict__ scales,
    s16x8* __restrict__ out) {
    int i = blockIdx.x * 256 + threadIdx.x;
    float s = scales[i >> 4];   // 8*i / 128
    float4 a = wq[2 * i];
    float4 b = wq[2 * i + 1];
    s16x8 r;
    r[0] = (short)f32_to_bf16(a.x * s); r[1] = (short)f32_to_bf16(a.y * s);
    r[2] = (short)f32_to_bf16(a.z * s); r[3] = (short)f32_to_bf16(a.w * s);
    r[4] = (short)f32_to_bf16(b.x * s); r[5] = (short)f32_to_bf16(b.y * s);
    r[6] = (short)f32_to_bf16(b.z * s); r[7] = (short)f32_to_bf16(b.w * s);
    out[i] = r;
}

// ---- async 16B global -> LDS ----
__device__ __forceinline__ void async_copy16(const unsigned short* g, unsigned short* l) {
    __builtin_amdgcn_global_load_lds(
        (const __attribute__((address_space(1))) unsigned int*)g,
        (__attribute__((address_space(3))) unsigned int*)l,
        16, 0, 0);
}

// ---- main GEMM: C[M,N] = A[M,K](bf16) * B[N,K]^T(bf16) + bias ----
// block = 256 threads (4 waves 2x2 over 128x128 C-tile); each wave: 4x4
// tiles of 16x16 via mfma_f32_16x16x32_bf16.  BK=32, single-buffered LDS.
__global__ __launch_bounds__(256) void gemm_bt_kernel(
    const unsigned short* __restrict__ A,   // M x K bf16 bits
    const unsigned short* __restrict__ B,   // N x K bf16 bits
    const float* __restrict__ bias,         // N
    float* __restrict__ C)                  // M x N
{
    __shared__ unsigned short lds_a[128 * 32];   // 8 KB
    __shared__ unsigned short lds_b[128 * 32];   // 8 KB

    const int t = threadIdx.x;
    const int w = t >> 6;          // wave 0..3
    const int l = t & 63;          // lane
    const int m0 = blockIdx.y * 128;
    const int n0 = blockIdx.x * 128;
    const int wm = (w & 1) * 64;   // wave row offset in tile
    const int wn = (w >> 1) * 64;  // wave col offset in tile

    // staging: chunk idx = pass*256 + t; row = idx>>2, chunk = idx&3 (8 bf16/chunk)
    const int srow = t >> 2;       // 0..63 (pass 0); pass 1 adds 64
    const int scol = (t & 3) * 8;  // element offset in row
    const unsigned short* gA = A + (long)(m0 + srow) * K_DIM + scol;
    const unsigned short* gB = B + (long)(n0 + srow) * K_DIM + scol;
    unsigned short* lA = lds_a + t * 8;       // byte offset t*16
    unsigned short* lB = lds_b + t * 8;

    // fragment addressing: row = base + (l&15), k-chunk = (l>>4)*8 elems
    const int fr = l & 15;
    const int fc = (l >> 4) * 8;

    f32x4 acc[4][4] = {};

    for (int kt = 0; kt < K_DIM / 32; ++kt) {
        const unsigned short* ga = gA + kt * 32;
        const unsigned short* gb = gB + kt * 32;
        async_copy16(ga,                lA);            // rows 0..63
        async_copy16(ga + 64 * K_DIM,   lA + 2048);     // rows 64..127
        async_copy16(gb,                lB);
        async_copy16(gb + 64 * K_DIM,   lB + 2048);
        __syncthreads();   // drains vmcnt (global_load_lds) + lgkmcnt

        s16x8 af[4], bf[4];
#pragma unroll
        for (int i = 0; i < 4; ++i)
            af[i] = *(const s16x8*)(lds_a + (wm + i * 16 + fr) * 32 + fc);
#pragma unroll
        for (int j = 0; j < 4; ++j)
            bf[j] = *(const s16x8*)(lds_b + (wn + j * 16 + fr) * 32 + fc);

#pragma unroll
        for (int i = 0; i < 4; ++i)
#pragma unroll
            for (int j = 0; j < 4; ++j)
                acc[i][j] = __builtin_amdgcn_mfma_f32_16x16x32_bf16(
                    af[i], bf[j], acc[i][j], 0, 0, 0);
        __syncthreads();
    }

    // epilogue: C/D layout row=(l>>4)*4+reg, col=l&15
    const int q = l >> 4;
#pragma unroll
    for (int j = 0; j < 4; ++j) {
        const int col = n0 + wn + j * 16 + (l & 15);
        const float bv = bias[col];
#pragma unroll
        for (int i = 0; i < 4; ++i) {
            const int row = m0 + wm + i * 16 + q * 4;
#pragma unroll
            for (int r = 0; r < 4; ++r) {
                C[(long)(row + r) * N_DIM + col] = acc[i][j][r] + bv;
            }
        }
    }
}

extern "C" void kernel_launch(void* const* d_in, const int* in_sizes, int n_in,
                              void* d_out, int out_size, void* d_ws, size_t ws_size,
                              hipStream_t stream) {
    const float* x      = (const float*)d_in[0];   // 2*4096*4096
    const float* wq     = (const float*)d_in[1];   // 4096*4096
    const float* scales = (const float*)d_in[2];   // 131072
    const float* bias   = (const float*)d_in[3];   // 4096
    float* out = (float*)d_out;

    // workspace layout: [0, 67108864) x_bf16 ; [67108864, 100663296) w_bf16
    unsigned short* x_bf = (unsigned short*)d_ws;
    unsigned short* w_bf = x_bf + (size_t)M_DIM * K_DIM;

    // x: 33554432 elems / 8 per thread = 4194304 threads
    cvt_x_kernel<<<16384, 256, 0, stream>>>((const float4*)x, (s16x8*)x_bf);
    // w: 16777216 elems / 8 per thread = 2097152 threads
    cvt_w_kernel<<<8192, 256, 0, stream>>>((const float4*)wq, scales, (s16x8*)w_bf);

    dim3 grid(N_DIM / 128, M_DIM / 128);   // (32, 64)
    gemm_bt_kernel<<<grid, 256, 0, stream>>>(x_bf, w_bf, bias, out);
}